// Round 9
// baseline (177.927 us; speedup 1.0000x reference)
//
#include <hip/hip_runtime.h>
#include <cstdint>
#include <cstddef>

#define N_NODES 50000
#define N_EDGES 640000
#define DF 128

#define NBUCK 196          // buckets of 256 nodes: bucket = dst >> 8
#define BCAP  6144         // staging capacity per bucket (mean 3265, +50 sigma)
#define PA_BLOCKS 250      // PassA blocks, 2560 edges each (250*2560 = 640000)
#define LPAD 136           // LDS row pitch (shorts): 16B-aligned, uniform bank spread

typedef __attribute__((ext_vector_type(8))) short bf16x8;
typedef __attribute__((ext_vector_type(4))) float f32x4;

__device__ inline unsigned short f2bf(float f) {            // RNE float->bf16
    unsigned int u = __float_as_uint(f);
    return (unsigned short)((u + 0x7fffu + ((u >> 16) & 1u)) >> 16);
}

// ================= K1: PassA (coarse bucket sort) || setup ===================
// blocks [0,250):        PassA — bin 2560 edges into 196 coarse buckets.
//   LDS count -> one global atomic per (block,bucket) reserves a contiguous
//   run -> packed 8B records {src|dstlocal<<16, w} stored in ~100B runs.
// blocks [250,6500):     featb = bf16(feat)
// blocks [6500,6524):    W fragments (B-operand order for 16x16x32 MFMA)
#define NF4 (N_NODES * DF / 4)        // 1,600,000
#define NWG (3 * 2048)
__global__ __launch_bounds__(256) void k1_setup_bucket(
    const float* __restrict__ feat,
    const float* __restrict__ W_pool,
    const float* __restrict__ W_neigh,
    const int* __restrict__ src,
    const int* __restrict__ dst,
    const float* __restrict__ w,
    unsigned short* __restrict__ featb,
    unsigned short* __restrict__ Wp_f,
    unsigned short* __restrict__ Wn1_f,
    unsigned short* __restrict__ Wn2_f,
    int* __restrict__ bucketcnt,        // pre-zeroed via hipMemsetAsync
    uint2* __restrict__ staging)
{
    int bid = blockIdx.x;
    int t = threadIdx.x;
    if (bid < PA_BLOCKS) {
        __shared__ int cnt[NBUCK];
        __shared__ int runbase[NBUCK];
        int base = bid * 2560;
        if (t < NBUCK) cnt[t] = 0;
        __syncthreads();
        uint2 rec[10];
        int bk[10];
        #pragma unroll
        for (int i = 0; i < 10; ++i) {
            int e = base + i * 256 + t;
            int s = src[e], d = dst[e];
            bk[i] = d >> 8;
            rec[i].x = (unsigned int)s | ((unsigned int)(d & 255) << 16);
            rec[i].y = __float_as_uint(w[e]);
            atomicAdd(&cnt[bk[i]], 1);
        }
        __syncthreads();
        if (t < NBUCK) {
            runbase[t] = atomicAdd(&bucketcnt[t], cnt[t]);
            cnt[t] = 0;                 // reuse as within-run cursor
        }
        __syncthreads();
        #pragma unroll
        for (int i = 0; i < 10; ++i) {
            int r = atomicAdd(&cnt[bk[i]], 1);
            int pos = runbase[bk[i]] + r;
            if (pos < BCAP) staging[bk[i] * BCAP + pos] = rec[i];
        }
    } else if (bid < 250 + NF4 / 256) {
        int idx = (bid - PA_BLOCKS) * 256 + t;
        float4 v = ((const float4*)feat)[idx];
        ushort4 o;
        o.x = f2bf(v.x); o.y = f2bf(v.y); o.z = f2bf(v.z); o.w = f2bf(v.w);
        ((ushort4*)featb)[idx] = o;
    } else {
        int g = (bid - PA_BLOCKS - NF4 / 256) * 256 + t;   // < NWG
        int m = g >> 11;
        int r8 = g & 2047;          // (c*4+tt)*64 + L
        int L = r8 & 63, tt = (r8 >> 6) & 3, c = r8 >> 8;
        int o = c * 16 + (L & 15);
        int kb = tt * 32 + (L >> 4) * 8;
        const float* srcp;
        unsigned short* dstp;
        if (m == 0)      { srcp = W_pool  + o * 128 + kb;       dstp = Wp_f;  }
        else if (m == 1) { srcp = W_neigh + o * 256 + kb;       dstp = Wn1_f; }
        else             { srcp = W_neigh + o * 256 + 128 + kb; dstp = Wn2_f; }
        ushort4 lo, hi;
        float4 a = ((const float4*)srcp)[0];
        float4 b = ((const float4*)srcp)[1];
        lo.x = f2bf(a.x); lo.y = f2bf(a.y); lo.z = f2bf(a.z); lo.w = f2bf(a.w);
        hi.x = f2bf(b.x); hi.y = f2bf(b.y); hi.z = f2bf(b.z); hi.w = f2bf(b.w);
        ((ushort4*)(dstp + r8 * 8))[0] = lo;
        ((ushort4*)(dstp + r8 * 8))[1] = hi;
    }
}

// ================= K2: gemm_pool || PassB (per-bucket fine sort) =============
// blocks [0,196):  gemm_pool — hb = bf16(featb @ Wp^T + b_pool), 16 waves/blk
// blocks [196,392): PassB — bucket b: base = prefix(bucketcnt), count+scan
//   per-node degrees in LDS, write offsets, re-scatter records into final
//   dst-sorted edges[] (stores confined to this block's ~26KB region).
#define GEMMB 196          // ceil(3125 waves / 16)
__global__ __launch_bounds__(1024) void k2_gemm_passb(
    const unsigned short* __restrict__ featb,
    const unsigned short* __restrict__ Wp_f,
    const float* __restrict__ b_pool,
    unsigned short* __restrict__ hb,
    const int* __restrict__ bucketcnt,
    const uint2* __restrict__ staging,
    int* __restrict__ offsets,
    uint2* __restrict__ edges)
{
    int t = threadIdx.x;
    if (blockIdx.x < GEMMB) {
        int wave = blockIdx.x * 16 + (t >> 6);
        int lane = t & 63;
        int m0 = wave * 16;
        if (m0 >= N_NODES) return;          // no barriers on this path
        const int n = lane & 15, quad = lane >> 4;

        f32x4 acc[8];
        #pragma unroll
        for (int c = 0; c < 8; ++c) {
            float bv = b_pool[c * 16 + n];
            acc[c] = (f32x4){bv, bv, bv, bv};
        }
        const unsigned short* aptr = featb + (size_t)(m0 + n) * DF + quad * 8;
        #pragma unroll
        for (int tt = 0; tt < 4; ++tt) {
            bf16x8 af = *(const bf16x8*)(aptr + tt * 32);
            #pragma unroll
            for (int c = 0; c < 8; ++c) {
                bf16x8 bf = *(const bf16x8*)(Wp_f + (size_t)((c * 4 + tt) * 64 + lane) * 8);
                acc[c] = __builtin_amdgcn_mfma_f32_16x16x32_bf16(af, bf, acc[c], 0, 0, 0);
            }
        }
        #pragma unroll
        for (int c = 0; c < 8; ++c)
            #pragma unroll
            for (int r = 0; r < 4; ++r)
                hb[(size_t)(m0 + quad * 4 + r) * DF + c * 16 + n] = f2bf(acc[c][r]);
    } else {
        __shared__ int dcnt[256];       // per-node count, then global cursor
        __shared__ int sc[256];         // scan scratch
        __shared__ int bc[256];         // bucket counts
        int b = blockIdx.x - GEMMB;     // 0..195

        if (t < 256) { dcnt[t] = 0; bc[t] = (t < NBUCK) ? bucketcnt[t] : 0; sc[t] = (t < NBUCK) ? bc[t] : 0; }
        __syncthreads();
        // exclusive prefix of bucket counts (Hillis-Steele over 256)
        #pragma unroll
        for (int off = 1; off < 256; off <<= 1) {
            int u = (t < 256 && t >= off) ? sc[t - off] : 0;
            __syncthreads();
            if (t < 256) sc[t] += u;
            __syncthreads();
        }
        int mybase = (b > 0) ? sc[b - 1] : 0;
        int cnt = bc[b];
        __syncthreads();                 // sc about to be reused

        // load my staged records, count per-node degrees
        uint2 rec[6];
        int nit = (cnt + 1023) >> 10;
        for (int i = 0; i < nit; ++i) {
            int idx = i * 1024 + t;
            if (idx < cnt) {
                rec[i] = staging[(size_t)b * BCAP + idx];
                atomicAdd(&dcnt[(rec[i].x >> 16) & 255], 1);
            }
        }
        __syncthreads();
        if (t < 256) sc[t] = dcnt[t];
        __syncthreads();
        #pragma unroll
        for (int off = 1; off < 256; off <<= 1) {
            int u = (t < 256 && t >= off) ? sc[t - off] : 0;
            __syncthreads();
            if (t < 256) sc[t] += u;
            __syncthreads();
        }
        if (t < 256) {
            int node = b * 256 + t;
            int excl = sc[t] - dcnt[t];
            if (node < N_NODES) offsets[node] = mybase + excl;
            dcnt[t] = mybase + excl;     // repurpose: global write cursor
        }
        if (b == NBUCK - 1 && t == 0) offsets[N_NODES] = mybase + cnt;
        __syncthreads();
        for (int i = 0; i < nit; ++i) {
            int idx = i * 1024 + t;
            if (idx < cnt) {
                int dl = (rec[i].x >> 16) & 255;
                int pos = atomicAdd(&dcnt[dl], 1);
                uint2 fin;
                fin.x = rec[i].x & 0xFFFFu;     // src
                fin.y = rec[i].y;               // w bits
                edges[pos] = fin;
            }
        }
    }
}

// ================= K3: fused gather-max (LDS) + output MFMA ==================
// 3125 blocks x 256. Block owns 16 output rows. Each of the 4 waves
// gather-maxes 4 nodes (R4's proven pattern: half-wave even/odd edge,
// 8 edges/iter, 4 concurrent 8B gathers) into a shared 16-row LDS tile,
// one __syncthreads (grid exact: 3125*16 = 50000, no early exit), then each
// wave computes a 16x32 slice: out = featb@Wn1^T + neighLDS@Wn2^T + bias.
// Low acc count (2 x f32x4) keeps VGPR <= 64 -> 8 blocks/CU, full MLP.
__global__ __launch_bounds__(256) void neigh_out(
    const unsigned short* __restrict__ featb,
    const unsigned short* __restrict__ hb,
    const int* __restrict__ offsets,
    const uint2* __restrict__ edges,
    const unsigned short* __restrict__ Wn1_f,
    const unsigned short* __restrict__ Wn2_f,
    const float* __restrict__ bias,
    float* __restrict__ out)
{
    __shared__ unsigned short nl[16 * LPAD];
    const int t = threadIdx.x;
    const int wv = t >> 6;           // wave 0..3
    const int lane = t & 63;
    const int m0 = blockIdx.x * 16;
    const int half = lane >> 5;      // 0: even edge of pair, 1: odd edge
    const int q = lane & 31;         // column quarter: cols 4q..4q+3

    // ---- stage 1: each wave gather-maxes 4 nodes into LDS rows wv*4..wv*4+3
    for (int i = 0; i < 4; ++i) {
        int node = m0 + wv * 4 + i;
        int beg = offsets[node], end = offsets[node + 1];
        float4 acc = make_float4(-3.4e38f, -3.4e38f, -3.4e38f, -3.4e38f);
        for (int e = beg; e < end; e += 8) {
            int i1 = min(e + 1, end - 1);
            int i2 = min(e + 2, end - 1);
            int i3 = min(e + 3, end - 1);
            int i4 = min(e + 4, end - 1);
            int i5 = min(e + 5, end - 1);
            int i6 = min(e + 6, end - 1);
            int i7 = min(e + 7, end - 1);
            uint2 e0 = edges[e],  e1 = edges[i1], e2 = edges[i2], e3 = edges[i3];
            uint2 e4 = edges[i4], e5 = edges[i5], e6 = edges[i6], e7 = edges[i7];
            uint2 mA = half ? e1 : e0;
            uint2 mB = half ? e3 : e2;
            uint2 mC = half ? e5 : e4;
            uint2 mD = half ? e7 : e6;
            float wA = __uint_as_float(mA.y);
            float wB = __uint_as_float(mB.y);
            float wC = __uint_as_float(mC.y);
            float wD = __uint_as_float(mD.y);
            uint2 pA = *(const uint2*)(hb + (size_t)mA.x * DF + q * 4);
            uint2 pB = *(const uint2*)(hb + (size_t)mB.x * DF + q * 4);
            uint2 pC = *(const uint2*)(hb + (size_t)mC.x * DF + q * 4);
            uint2 pD = *(const uint2*)(hb + (size_t)mD.x * DF + q * 4);
            acc.x = fmaxf(acc.x, __uint_as_float(pA.x << 16)          * wA);
            acc.y = fmaxf(acc.y, __uint_as_float(pA.x & 0xffff0000u)  * wA);
            acc.z = fmaxf(acc.z, __uint_as_float(pA.y << 16)          * wA);
            acc.w = fmaxf(acc.w, __uint_as_float(pA.y & 0xffff0000u)  * wA);
            acc.x = fmaxf(acc.x, __uint_as_float(pB.x << 16)          * wB);
            acc.y = fmaxf(acc.y, __uint_as_float(pB.x & 0xffff0000u)  * wB);
            acc.z = fmaxf(acc.z, __uint_as_float(pB.y << 16)          * wB);
            acc.w = fmaxf(acc.w, __uint_as_float(pB.y & 0xffff0000u)  * wB);
            acc.x = fmaxf(acc.x, __uint_as_float(pC.x << 16)          * wC);
            acc.y = fmaxf(acc.y, __uint_as_float(pC.x & 0xffff0000u)  * wC);
            acc.z = fmaxf(acc.z, __uint_as_float(pC.y << 16)          * wC);
            acc.w = fmaxf(acc.w, __uint_as_float(pC.y & 0xffff0000u)  * wC);
            acc.x = fmaxf(acc.x, __uint_as_float(pD.x << 16)          * wD);
            acc.y = fmaxf(acc.y, __uint_as_float(pD.x & 0xffff0000u)  * wD);
            acc.z = fmaxf(acc.z, __uint_as_float(pD.y << 16)          * wD);
            acc.w = fmaxf(acc.w, __uint_as_float(pD.y & 0xffff0000u)  * wD);
        }
        float4 o;
        o.x = fmaxf(acc.x, __shfl_xor(acc.x, 32));
        o.y = fmaxf(acc.y, __shfl_xor(acc.y, 32));
        o.z = fmaxf(acc.z, __shfl_xor(acc.z, 32));
        o.w = fmaxf(acc.w, __shfl_xor(acc.w, 32));
        if (beg == end) o = make_float4(0.f, 0.f, 0.f, 0.f);
        if (half == 0) {
            ushort4 ob;
            ob.x = f2bf(o.x); ob.y = f2bf(o.y); ob.z = f2bf(o.z); ob.w = f2bf(o.w);
            *(ushort4*)(&nl[(wv * 4 + i) * LPAD + q * 4]) = ob;
        }
    }
    __syncthreads();

    // ---- stage 2: wave wv computes cols [wv*32, wv*32+32) of the 16-row tile
    const int n = lane & 15, quad = lane >> 4;
    f32x4 acc[2];
    #pragma unroll
    for (int cc = 0; cc < 2; ++cc) {
        float bv = bias[(wv * 2 + cc) * 16 + n];
        acc[cc] = (f32x4){bv, bv, bv, bv};
    }

    const unsigned short* a0 = featb + (size_t)(m0 + n) * DF + quad * 8;
    #pragma unroll
    for (int tt = 0; tt < 4; ++tt) {
        bf16x8 af = *(const bf16x8*)(a0 + tt * 32);
        #pragma unroll
        for (int cc = 0; cc < 2; ++cc) {
            int c = wv * 2 + cc;
            bf16x8 bf = *(const bf16x8*)(Wn1_f + (size_t)((c * 4 + tt) * 64 + lane) * 8);
            acc[cc] = __builtin_amdgcn_mfma_f32_16x16x32_bf16(af, bf, acc[cc], 0, 0, 0);
        }
    }
    #pragma unroll
    for (int tt = 0; tt < 4; ++tt) {
        bf16x8 af = *(const bf16x8*)(&nl[n * LPAD + tt * 32 + quad * 8]);
        #pragma unroll
        for (int cc = 0; cc < 2; ++cc) {
            int c = wv * 2 + cc;
            bf16x8 bf = *(const bf16x8*)(Wn2_f + (size_t)((c * 4 + tt) * 64 + lane) * 8);
            acc[cc] = __builtin_amdgcn_mfma_f32_16x16x32_bf16(af, bf, acc[cc], 0, 0, 0);
        }
    }

    // D layout: lane holds D[quad*4+r][c*16+n]
    #pragma unroll
    for (int cc = 0; cc < 2; ++cc)
        #pragma unroll
        for (int r = 0; r < 4; ++r)
            out[(size_t)(m0 + quad * 4 + r) * DF + (wv * 2 + cc) * 16 + n] = acc[cc][r];
}

extern "C" void kernel_launch(void* const* d_in, const int* in_sizes, int n_in,
                              void* d_out, int out_size, void* d_ws, size_t ws_size,
                              hipStream_t stream) {
    const float* feat    = (const float*)d_in[0];
    const float* weight  = (const float*)d_in[1];
    const int*   src     = (const int*)d_in[2];
    const int*   dst     = (const int*)d_in[3];
    const float* W_pool  = (const float*)d_in[4];
    const float* b_pool  = (const float*)d_in[5];
    const float* W_neigh = (const float*)d_in[6];
    const float* b_neigh = (const float*)d_in[7];
    float* out = (float*)d_out;

    char* ws = (char*)d_ws;
    unsigned short* featb  = (unsigned short*)(ws);              // 12,800,000 B
    unsigned short* hb     = (unsigned short*)(ws + 12800000);   // 12,800,000 B
    unsigned short* Wp_f   = (unsigned short*)(ws + 25600000);   // 32,768 B
    unsigned short* Wn1_f  = (unsigned short*)(ws + 25632768);   // 32,768 B
    unsigned short* Wn2_f  = (unsigned short*)(ws + 25665536);   // 32,768 B
    int*   offsets   = (int*)  (ws + 25698304);                  // 200,064 B
    int*   bucketcnt = (int*)  (ws + 25898368);                  // 1,024 B
    uint2* staging   = (uint2*)(ws + 25899392);                  // 9,633,792 B
    uint2* edges     = (uint2*)(ws + 35533184);                  // 5,120,000 B -> ~40.7 MB

    hipMemsetAsync(bucketcnt, 0, 1024, stream);

    // K1: PassA (coarse bucket scatter) || featb conversion || W fragments
    const int K1_BLOCKS = PA_BLOCKS + NF4 / 256 + NWG / 256;   // 250+6250+24
    k1_setup_bucket<<<K1_BLOCKS, 256, 0, stream>>>(
        feat, W_pool, W_neigh, src, dst, weight,
        featb, Wp_f, Wn1_f, Wn2_f, bucketcnt, staging);

    // K2: gemm_pool (hb) || PassB (offsets + final dst-sorted edges)
    k2_gemm_passb<<<GEMMB + NBUCK, 1024, 0, stream>>>(
        featb, Wp_f, b_pool, hb, bucketcnt, staging, offsets, edges);

    // K3: fused segment-max gather (LDS tile) + out = featb@Wn1^T + neigh@Wn2^T + b
    neigh_out<<<N_NODES / 16, 256, 0, stream>>>(
        featb, hb, offsets, edges, Wn1_f, Wn2_f, b_neigh, out);
}

// Round 10
// 168.031 us; speedup vs baseline: 1.0589x; 1.0589x over previous
//
#include <hip/hip_runtime.h>
#include <cstdint>
#include <cstddef>

#define N_NODES 50000
#define N_EDGES 640000
#define DF 128

#define NBUCK 196          // buckets of 256 nodes: bucket = dst >> 8
#define BCAP  6144         // staging capacity per bucket (mean 3265, +50 sigma)
#define PA_BLOCKS 250      // PassA blocks, 2560 edges each (250*2560 = 640000)

typedef __attribute__((ext_vector_type(8))) short bf16x8;
typedef __attribute__((ext_vector_type(4))) float f32x4;

__device__ inline unsigned short f2bf(float f) {            // RNE float->bf16
    unsigned int u = __float_as_uint(f);
    return (unsigned short)((u + 0x7fffu + ((u >> 16) & 1u)) >> 16);
}

// ================= K1: PassA (coarse bucket sort) || setup ===================
// blocks [0,250):        PassA — bin 2560 edges into 196 coarse buckets.
//   LDS count -> one global atomic per (block,bucket) reserves a contiguous
//   run -> packed 8B records {src|dstlocal<<16, w} stored in ~100B runs.
// blocks [250,6500):     featb = bf16(feat)
// blocks [6500,6524):    W fragments (B-operand order for 16x16x32 MFMA)
#define NF4 (N_NODES * DF / 4)        // 1,600,000
#define NWG (3 * 2048)
__global__ __launch_bounds__(256) void k1_setup_bucket(
    const float* __restrict__ feat,
    const float* __restrict__ W_pool,
    const float* __restrict__ W_neigh,
    const int* __restrict__ src,
    const int* __restrict__ dst,
    const float* __restrict__ w,
    unsigned short* __restrict__ featb,
    unsigned short* __restrict__ Wp_f,
    unsigned short* __restrict__ Wn1_f,
    unsigned short* __restrict__ Wn2_f,
    int* __restrict__ bucketcnt,        // pre-zeroed via hipMemsetAsync
    uint2* __restrict__ staging)
{
    int bid = blockIdx.x;
    int t = threadIdx.x;
    if (bid < PA_BLOCKS) {
        __shared__ int cnt[NBUCK];
        __shared__ int runbase[NBUCK];
        int base = bid * 2560;
        if (t < NBUCK) cnt[t] = 0;
        __syncthreads();
        uint2 rec[10];
        int bk[10];
        #pragma unroll
        for (int i = 0; i < 10; ++i) {
            int e = base + i * 256 + t;
            int s = src[e], d = dst[e];
            bk[i] = d >> 8;
            rec[i].x = (unsigned int)s | ((unsigned int)(d & 255) << 16);
            rec[i].y = __float_as_uint(w[e]);
            atomicAdd(&cnt[bk[i]], 1);
        }
        __syncthreads();
        if (t < NBUCK) {
            runbase[t] = atomicAdd(&bucketcnt[t], cnt[t]);
            cnt[t] = 0;                 // reuse as within-run cursor
        }
        __syncthreads();
        #pragma unroll
        for (int i = 0; i < 10; ++i) {
            int r = atomicAdd(&cnt[bk[i]], 1);
            int pos = runbase[bk[i]] + r;
            if (pos < BCAP) staging[bk[i] * BCAP + pos] = rec[i];
        }
    } else if (bid < 250 + NF4 / 256) {
        int idx = (bid - PA_BLOCKS) * 256 + t;
        float4 v = ((const float4*)feat)[idx];
        ushort4 o;
        o.x = f2bf(v.x); o.y = f2bf(v.y); o.z = f2bf(v.z); o.w = f2bf(v.w);
        ((ushort4*)featb)[idx] = o;
    } else {
        int g = (bid - PA_BLOCKS - NF4 / 256) * 256 + t;   // < NWG
        int m = g >> 11;
        int r8 = g & 2047;          // (c*4+tt)*64 + L
        int L = r8 & 63, tt = (r8 >> 6) & 3, c = r8 >> 8;
        int o = c * 16 + (L & 15);
        int kb = tt * 32 + (L >> 4) * 8;
        const float* srcp;
        unsigned short* dstp;
        if (m == 0)      { srcp = W_pool  + o * 128 + kb;       dstp = Wp_f;  }
        else if (m == 1) { srcp = W_neigh + o * 256 + kb;       dstp = Wn1_f; }
        else             { srcp = W_neigh + o * 256 + 128 + kb; dstp = Wn2_f; }
        ushort4 lo, hi;
        float4 a = ((const float4*)srcp)[0];
        float4 b = ((const float4*)srcp)[1];
        lo.x = f2bf(a.x); lo.y = f2bf(a.y); lo.z = f2bf(a.z); lo.w = f2bf(a.w);
        hi.x = f2bf(b.x); hi.y = f2bf(b.y); hi.z = f2bf(b.z); hi.w = f2bf(b.w);
        ((ushort4*)(dstp + r8 * 8))[0] = lo;
        ((ushort4*)(dstp + r8 * 8))[1] = hi;
    }
}

// ================= K2: gemm_pool || PassB (per-bucket fine sort) =============
// blocks [0,196):  gemm_pool — hb = bf16(featb @ Wp^T + b_pool), 16 waves/blk
// blocks [196,392): PassB — bucket b: base = prefix(bucketcnt), count+scan
//   per-node degrees in LDS, write offsets, re-scatter records into final
//   dst-sorted edges[] (stores confined to this block's ~26KB region).
#define GEMMB 196          // ceil(3125 waves / 16)
__global__ __launch_bounds__(1024) void k2_gemm_passb(
    const unsigned short* __restrict__ featb,
    const unsigned short* __restrict__ Wp_f,
    const float* __restrict__ b_pool,
    unsigned short* __restrict__ hb,
    const int* __restrict__ bucketcnt,
    const uint2* __restrict__ staging,
    int* __restrict__ offsets,
    uint2* __restrict__ edges)
{
    int t = threadIdx.x;
    if (blockIdx.x < GEMMB) {
        int wave = blockIdx.x * 16 + (t >> 6);
        int lane = t & 63;
        int m0 = wave * 16;
        if (m0 >= N_NODES) return;          // no barriers on this path
        const int n = lane & 15, quad = lane >> 4;

        f32x4 acc[8];
        #pragma unroll
        for (int c = 0; c < 8; ++c) {
            float bv = b_pool[c * 16 + n];
            acc[c] = (f32x4){bv, bv, bv, bv};
        }
        const unsigned short* aptr = featb + (size_t)(m0 + n) * DF + quad * 8;
        #pragma unroll
        for (int tt = 0; tt < 4; ++tt) {
            bf16x8 af = *(const bf16x8*)(aptr + tt * 32);
            #pragma unroll
            for (int c = 0; c < 8; ++c) {
                bf16x8 bf = *(const bf16x8*)(Wp_f + (size_t)((c * 4 + tt) * 64 + lane) * 8);
                acc[c] = __builtin_amdgcn_mfma_f32_16x16x32_bf16(af, bf, acc[c], 0, 0, 0);
            }
        }
        #pragma unroll
        for (int c = 0; c < 8; ++c)
            #pragma unroll
            for (int r = 0; r < 4; ++r)
                hb[(size_t)(m0 + quad * 4 + r) * DF + c * 16 + n] = f2bf(acc[c][r]);
    } else {
        __shared__ int dcnt[256];       // per-node count, then global cursor
        __shared__ int sc[256];         // scan scratch
        __shared__ int bc[256];         // bucket counts
        int b = blockIdx.x - GEMMB;     // 0..195

        if (t < 256) { dcnt[t] = 0; bc[t] = (t < NBUCK) ? bucketcnt[t] : 0; sc[t] = (t < NBUCK) ? bc[t] : 0; }
        __syncthreads();
        // exclusive prefix of bucket counts (Hillis-Steele over 256)
        #pragma unroll
        for (int off = 1; off < 256; off <<= 1) {
            int u = (t < 256 && t >= off) ? sc[t - off] : 0;
            __syncthreads();
            if (t < 256) sc[t] += u;
            __syncthreads();
        }
        int mybase = (b > 0) ? sc[b - 1] : 0;
        int cnt = bc[b];
        __syncthreads();                 // sc about to be reused

        // load my staged records, count per-node degrees
        uint2 rec[6];
        int nit = (cnt + 1023) >> 10;
        for (int i = 0; i < nit; ++i) {
            int idx = i * 1024 + t;
            if (idx < cnt) {
                rec[i] = staging[(size_t)b * BCAP + idx];
                atomicAdd(&dcnt[(rec[i].x >> 16) & 255], 1);
            }
        }
        __syncthreads();
        if (t < 256) sc[t] = dcnt[t];
        __syncthreads();
        #pragma unroll
        for (int off = 1; off < 256; off <<= 1) {
            int u = (t < 256 && t >= off) ? sc[t - off] : 0;
            __syncthreads();
            if (t < 256) sc[t] += u;
            __syncthreads();
        }
        if (t < 256) {
            int node = b * 256 + t;
            int excl = sc[t] - dcnt[t];
            if (node < N_NODES) offsets[node] = mybase + excl;
            dcnt[t] = mybase + excl;     // repurpose: global write cursor
        }
        if (b == NBUCK - 1 && t == 0) offsets[N_NODES] = mybase + cnt;
        __syncthreads();
        for (int i = 0; i < nit; ++i) {
            int idx = i * 1024 + t;
            if (idx < cnt) {
                int dl = (rec[i].x >> 16) & 255;
                int pos = atomicAdd(&dcnt[dl], 1);
                uint2 fin;
                fin.x = rec[i].x & 0xFFFFu;     // src
                fin.y = rec[i].y;               // w bits
                edges[pos] = fin;
            }
        }
    }
}

// ================= K3: per-node max over incoming messages (1 wave/node) ====
// hb bf16 (row = 256 B). Half-wave gathers even/odd edge of a pair; 16 edges
// per iteration -> 8 independent 8B gathers in flight (deg<=16 nodes finish
// the gather chain in ONE round; mean degree 12.8). Output bf16.
__global__ __launch_bounds__(256) void neigh_max_kernel(
    const unsigned short* __restrict__ hb, const int* __restrict__ offsets,
    const uint2* __restrict__ edges,
    unsigned short* __restrict__ neighb)
{
    int gwave = (blockIdx.x * 256 + threadIdx.x) >> 6;
    if (gwave >= N_NODES) return;
    int node = __builtin_amdgcn_readfirstlane(gwave);
    int lane = threadIdx.x & 63;
    const int half = lane >> 5;      // 0: even edge of pair, 1: odd edge
    const int q = lane & 31;         // column quarter: cols 4q..4q+3

    int beg = offsets[node], end = offsets[node + 1];
    float4 acc = make_float4(-3.4e38f, -3.4e38f, -3.4e38f, -3.4e38f);

    for (int e = beg; e < end; e += 16) {
        uint2 meta[8];
        #pragma unroll
        for (int j = 0; j < 8; ++j) {
            int idx = min(e + 2 * j + half, end - 1);
            meta[j] = edges[idx];
        }
        uint2 p[8];
        #pragma unroll
        for (int j = 0; j < 8; ++j)
            p[j] = *(const uint2*)(hb + (size_t)meta[j].x * DF + q * 4);
        #pragma unroll
        for (int j = 0; j < 8; ++j) {
            float wj = __uint_as_float(meta[j].y);
            acc.x = fmaxf(acc.x, __uint_as_float(p[j].x << 16)         * wj);
            acc.y = fmaxf(acc.y, __uint_as_float(p[j].x & 0xffff0000u) * wj);
            acc.z = fmaxf(acc.z, __uint_as_float(p[j].y << 16)         * wj);
            acc.w = fmaxf(acc.w, __uint_as_float(p[j].y & 0xffff0000u) * wj);
        }
    }

    float4 o;
    o.x = fmaxf(acc.x, __shfl_xor(acc.x, 32));
    o.y = fmaxf(acc.y, __shfl_xor(acc.y, 32));
    o.z = fmaxf(acc.z, __shfl_xor(acc.z, 32));
    o.w = fmaxf(acc.w, __shfl_xor(acc.w, 32));
    if (beg == end) o = make_float4(0.f, 0.f, 0.f, 0.f);
    if (half == 0) {
        ushort4 ob;
        ob.x = f2bf(o.x); ob.y = f2bf(o.y); ob.z = f2bf(o.z); ob.w = f2bf(o.w);
        *(ushort4*)(neighb + (size_t)node * DF + q * 4) = ob;
    }
}

// ================= K4: out = featb@Wn1^T + neighb@Wn2^T + b_neigh (fp32) ====
__global__ __launch_bounds__(256) void gemm_out(
    const unsigned short* __restrict__ featb,
    const unsigned short* __restrict__ neighb,
    const unsigned short* __restrict__ Wn1_f,
    const unsigned short* __restrict__ Wn2_f,
    const float* __restrict__ bias,
    float* __restrict__ out)
{
    int wave = (blockIdx.x * 256 + threadIdx.x) >> 6;
    int lane = threadIdx.x & 63;
    int m0 = wave * 16;
    if (m0 >= N_NODES) return;
    const int n = lane & 15, quad = lane >> 4;

    f32x4 acc[8];
    #pragma unroll
    for (int c = 0; c < 8; ++c) {
        float bv = bias[c * 16 + n];
        acc[c] = (f32x4){bv, bv, bv, bv};
    }

    const unsigned short* a0 = featb  + (size_t)(m0 + n) * DF + quad * 8;
    const unsigned short* a1 = neighb + (size_t)(m0 + n) * DF + quad * 8;
    #pragma unroll
    for (int t = 0; t < 4; ++t) {
        bf16x8 af = *(const bf16x8*)(a0 + t * 32);
        #pragma unroll
        for (int c = 0; c < 8; ++c) {
            bf16x8 bf = *(const bf16x8*)(Wn1_f + (size_t)((c * 4 + t) * 64 + lane) * 8);
            acc[c] = __builtin_amdgcn_mfma_f32_16x16x32_bf16(af, bf, acc[c], 0, 0, 0);
        }
    }
    #pragma unroll
    for (int t = 0; t < 4; ++t) {
        bf16x8 af = *(const bf16x8*)(a1 + t * 32);
        #pragma unroll
        for (int c = 0; c < 8; ++c) {
            bf16x8 bf = *(const bf16x8*)(Wn2_f + (size_t)((c * 4 + t) * 64 + lane) * 8);
            acc[c] = __builtin_amdgcn_mfma_f32_16x16x32_bf16(af, bf, acc[c], 0, 0, 0);
        }
    }

    #pragma unroll
    for (int c = 0; c < 8; ++c)
        #pragma unroll
        for (int r = 0; r < 4; ++r)
            out[(size_t)(m0 + quad * 4 + r) * DF + c * 16 + n] = acc[c][r];
}

extern "C" void kernel_launch(void* const* d_in, const int* in_sizes, int n_in,
                              void* d_out, int out_size, void* d_ws, size_t ws_size,
                              hipStream_t stream) {
    const float* feat    = (const float*)d_in[0];
    const float* weight  = (const float*)d_in[1];
    const int*   src     = (const int*)d_in[2];
    const int*   dst     = (const int*)d_in[3];
    const float* W_pool  = (const float*)d_in[4];
    const float* b_pool  = (const float*)d_in[5];
    const float* W_neigh = (const float*)d_in[6];
    const float* b_neigh = (const float*)d_in[7];
    float* out = (float*)d_out;

    char* ws = (char*)d_ws;
    unsigned short* featb  = (unsigned short*)(ws);              // 12,800,000 B
    unsigned short* hb     = (unsigned short*)(ws + 12800000);   // 12,800,000 B
    unsigned short* neighb = (unsigned short*)(ws + 25600000);   // 12,800,000 B
    unsigned short* Wp_f   = (unsigned short*)(ws + 38400000);   // 32,768 B
    unsigned short* Wn1_f  = (unsigned short*)(ws + 38432768);   // 32,768 B
    unsigned short* Wn2_f  = (unsigned short*)(ws + 38465536);   // 32,768 B
    int*   offsets   = (int*)  (ws + 38498304);                  // 200,064 B
    int*   bucketcnt = (int*)  (ws + 38698368);                  // 1,024 B
    uint2* staging   = (uint2*)(ws + 38699392);                  // 9,633,792 B
    uint2* edges     = (uint2*)(ws + 48333184);                  // 5,120,000 B -> ~53.5 MB

    hipMemsetAsync(bucketcnt, 0, 1024, stream);

    // K1: PassA (coarse bucket scatter) || featb conversion || W fragments
    const int K1_BLOCKS = PA_BLOCKS + NF4 / 256 + NWG / 256;   // 250+6250+24
    k1_setup_bucket<<<K1_BLOCKS, 256, 0, stream>>>(
        feat, W_pool, W_neigh, src, dst, weight,
        featb, Wp_f, Wn1_f, Wn2_f, bucketcnt, staging);

    // K2: gemm_pool (hb) || PassB (offsets + final dst-sorted edges)
    k2_gemm_passb<<<GEMMB + NBUCK, 1024, 0, stream>>>(
        featb, Wp_f, b_pool, hb, bucketcnt, staging, offsets, edges);

    // K3: neighb = bf16(segment_max(hb[src]*w, dst)), 0 for empty
    neigh_max_kernel<<<(N_NODES + 3) / 4, 256, 0, stream>>>(hb, offsets, edges, neighb);

    // K4: out = featb @ Wn1^T + neighb @ Wn2^T + b_neigh
    gemm_out<<<782, 256, 0, stream>>>(
        featb, neighb, Wn1_f, Wn2_f, b_neigh, out);
}

// Round 11
// 162.712 us; speedup vs baseline: 1.0935x; 1.0327x over previous
//
#include <hip/hip_runtime.h>
#include <cstdint>
#include <cstddef>

#define N_NODES 50000
#define N_EDGES 640000
#define DF 128

#define NBUCK 196          // buckets of 256 nodes: bucket = dst >> 8
#define BCAP  6144         // staging capacity per bucket (mean 3265, +50 sigma)
#define PA_BLOCKS 250      // PassA blocks, 2560 edges each (250*2560 = 640000)

typedef __attribute__((ext_vector_type(8))) short bf16x8;
typedef __attribute__((ext_vector_type(4))) float f32x4;

__device__ inline unsigned short f2bf(float f) {            // RNE float->bf16
    unsigned int u = __float_as_uint(f);
    return (unsigned short)((u + 0x7fffu + ((u >> 16) & 1u)) >> 16);
}

// ================= K1: PassA (coarse bucket sort) || setup ===================
// blocks [0,250):        PassA — bin 2560 edges into 196 coarse buckets.
//   LDS count -> one global atomic per (block,bucket) reserves a contiguous
//   run -> packed 8B records {src|dstlocal<<16, w} stored in ~100B runs.
// blocks [250,6500):     featb = bf16(feat)
// blocks [6500,6524):    W fragments (B-operand order for 16x16x32 MFMA)
#define NF4 (N_NODES * DF / 4)        // 1,600,000
#define NWG (3 * 2048)
__global__ __launch_bounds__(256) void k1_setup_bucket(
    const float* __restrict__ feat,
    const float* __restrict__ W_pool,
    const float* __restrict__ W_neigh,
    const int* __restrict__ src,
    const int* __restrict__ dst,
    const float* __restrict__ w,
    unsigned short* __restrict__ featb,
    unsigned short* __restrict__ Wp_f,
    unsigned short* __restrict__ Wn1_f,
    unsigned short* __restrict__ Wn2_f,
    int* __restrict__ bucketcnt,        // pre-zeroed via hipMemsetAsync
    uint2* __restrict__ staging)
{
    int bid = blockIdx.x;
    int t = threadIdx.x;
    if (bid < PA_BLOCKS) {
        __shared__ int cnt[NBUCK];
        __shared__ int runbase[NBUCK];
        int base = bid * 2560;
        if (t < NBUCK) cnt[t] = 0;
        __syncthreads();
        uint2 rec[10];
        int bk[10];
        #pragma unroll
        for (int i = 0; i < 10; ++i) {
            int e = base + i * 256 + t;
            int s = src[e], d = dst[e];
            bk[i] = d >> 8;
            rec[i].x = (unsigned int)s | ((unsigned int)(d & 255) << 16);
            rec[i].y = __float_as_uint(w[e]);
            atomicAdd(&cnt[bk[i]], 1);
        }
        __syncthreads();
        if (t < NBUCK) {
            runbase[t] = atomicAdd(&bucketcnt[t], cnt[t]);
            cnt[t] = 0;                 // reuse as within-run cursor
        }
        __syncthreads();
        #pragma unroll
        for (int i = 0; i < 10; ++i) {
            int r = atomicAdd(&cnt[bk[i]], 1);
            int pos = runbase[bk[i]] + r;
            if (pos < BCAP) staging[bk[i] * BCAP + pos] = rec[i];
        }
    } else if (bid < 250 + NF4 / 256) {
        int idx = (bid - PA_BLOCKS) * 256 + t;
        float4 v = ((const float4*)feat)[idx];
        ushort4 o;
        o.x = f2bf(v.x); o.y = f2bf(v.y); o.z = f2bf(v.z); o.w = f2bf(v.w);
        ((ushort4*)featb)[idx] = o;
    } else {
        int g = (bid - PA_BLOCKS - NF4 / 256) * 256 + t;   // < NWG
        int m = g >> 11;
        int r8 = g & 2047;          // (c*4+tt)*64 + L
        int L = r8 & 63, tt = (r8 >> 6) & 3, c = r8 >> 8;
        int o = c * 16 + (L & 15);
        int kb = tt * 32 + (L >> 4) * 8;
        const float* srcp;
        unsigned short* dstp;
        if (m == 0)      { srcp = W_pool  + o * 128 + kb;       dstp = Wp_f;  }
        else if (m == 1) { srcp = W_neigh + o * 256 + kb;       dstp = Wn1_f; }
        else             { srcp = W_neigh + o * 256 + 128 + kb; dstp = Wn2_f; }
        ushort4 lo, hi;
        float4 a = ((const float4*)srcp)[0];
        float4 b = ((const float4*)srcp)[1];
        lo.x = f2bf(a.x); lo.y = f2bf(a.y); lo.z = f2bf(a.z); lo.w = f2bf(a.w);
        hi.x = f2bf(b.x); hi.y = f2bf(b.y); hi.z = f2bf(b.z); hi.w = f2bf(b.w);
        ((ushort4*)(dstp + r8 * 8))[0] = lo;
        ((ushort4*)(dstp + r8 * 8))[1] = hi;
    }
}

// ================= K2: gemm_pool || PassB (per-bucket fine sort) =============
// blocks [0,196):  gemm_pool — hb = bf16(featb @ Wp^T + b_pool), 16 waves/blk
// blocks [196,392): PassB — bucket b: base = prefix(bucketcnt), count+scan
//   per-node degrees in LDS, write offsets, re-scatter records into final
//   dst-sorted edges[] (stores confined to this block's ~26KB region).
#define GEMMB 196          // ceil(3125 waves / 16)
__global__ __launch_bounds__(1024) void k2_gemm_passb(
    const unsigned short* __restrict__ featb,
    const unsigned short* __restrict__ Wp_f,
    const float* __restrict__ b_pool,
    unsigned short* __restrict__ hb,
    const int* __restrict__ bucketcnt,
    const uint2* __restrict__ staging,
    int* __restrict__ offsets,
    uint2* __restrict__ edges)
{
    int t = threadIdx.x;
    if (blockIdx.x < GEMMB) {
        int wave = blockIdx.x * 16 + (t >> 6);
        int lane = t & 63;
        int m0 = wave * 16;
        if (m0 >= N_NODES) return;          // no barriers on this path
        const int n = lane & 15, quad = lane >> 4;

        f32x4 acc[8];
        #pragma unroll
        for (int c = 0; c < 8; ++c) {
            float bv = b_pool[c * 16 + n];
            acc[c] = (f32x4){bv, bv, bv, bv};
        }
        const unsigned short* aptr = featb + (size_t)(m0 + n) * DF + quad * 8;
        #pragma unroll
        for (int tt = 0; tt < 4; ++tt) {
            bf16x8 af = *(const bf16x8*)(aptr + tt * 32);
            #pragma unroll
            for (int c = 0; c < 8; ++c) {
                bf16x8 bf = *(const bf16x8*)(Wp_f + (size_t)((c * 4 + tt) * 64 + lane) * 8);
                acc[c] = __builtin_amdgcn_mfma_f32_16x16x32_bf16(af, bf, acc[c], 0, 0, 0);
            }
        }
        #pragma unroll
        for (int c = 0; c < 8; ++c)
            #pragma unroll
            for (int r = 0; r < 4; ++r)
                hb[(size_t)(m0 + quad * 4 + r) * DF + c * 16 + n] = f2bf(acc[c][r]);
    } else {
        __shared__ int dcnt[256];       // per-node count, then global cursor
        __shared__ int sc[256];         // scan scratch
        __shared__ int bc[256];         // bucket counts
        int b = blockIdx.x - GEMMB;     // 0..195

        if (t < 256) { dcnt[t] = 0; bc[t] = (t < NBUCK) ? bucketcnt[t] : 0; sc[t] = (t < NBUCK) ? bc[t] : 0; }
        __syncthreads();
        // exclusive prefix of bucket counts (Hillis-Steele over 256)
        #pragma unroll
        for (int off = 1; off < 256; off <<= 1) {
            int u = (t < 256 && t >= off) ? sc[t - off] : 0;
            __syncthreads();
            if (t < 256) sc[t] += u;
            __syncthreads();
        }
        int mybase = (b > 0) ? sc[b - 1] : 0;
        int cnt = bc[b];
        __syncthreads();                 // sc about to be reused

        // load my staged records, count per-node degrees
        uint2 rec[6];
        int nit = (cnt + 1023) >> 10;
        for (int i = 0; i < nit; ++i) {
            int idx = i * 1024 + t;
            if (idx < cnt) {
                rec[i] = staging[(size_t)b * BCAP + idx];
                atomicAdd(&dcnt[(rec[i].x >> 16) & 255], 1);
            }
        }
        __syncthreads();
        if (t < 256) sc[t] = dcnt[t];
        __syncthreads();
        #pragma unroll
        for (int off = 1; off < 256; off <<= 1) {
            int u = (t < 256 && t >= off) ? sc[t - off] : 0;
            __syncthreads();
            if (t < 256) sc[t] += u;
            __syncthreads();
        }
        if (t < 256) {
            int node = b * 256 + t;
            int excl = sc[t] - dcnt[t];
            if (node < N_NODES) offsets[node] = mybase + excl;
            dcnt[t] = mybase + excl;     // repurpose: global write cursor
        }
        if (b == NBUCK - 1 && t == 0) offsets[N_NODES] = mybase + cnt;
        __syncthreads();
        for (int i = 0; i < nit; ++i) {
            int idx = i * 1024 + t;
            if (idx < cnt) {
                int dl = (rec[i].x >> 16) & 255;
                int pos = atomicAdd(&dcnt[dl], 1);
                uint2 fin;
                fin.x = rec[i].x & 0xFFFFu;     // src
                fin.y = rec[i].y;               // w bits
                edges[pos] = fin;
            }
        }
    }
}

// ================= K3: per-node max over incoming messages (1 wave/node) ====
// hb bf16 (row = 256 B). Half-wave gathers even/odd edge of a pair; 8 edges
// per iteration -> 4 independent 8B gathers in flight. Output bf16.
// NOTE (R9 post-mortem): 16-edge unroll REGRESSED (+5 us) — VGPR growth cut
// occupancy, and the gather is L3-BW-bound (~6 TB/s effective) not
// latency-bound. Keep the 8-edge / low-VGPR form.
__global__ __launch_bounds__(256) void neigh_max_kernel(
    const unsigned short* __restrict__ hb, const int* __restrict__ offsets,
    const uint2* __restrict__ edges,
    unsigned short* __restrict__ neighb)
{
    int gwave = (blockIdx.x * 256 + threadIdx.x) >> 6;
    if (gwave >= N_NODES) return;
    int node = __builtin_amdgcn_readfirstlane(gwave);
    int lane = threadIdx.x & 63;
    const int half = lane >> 5;      // 0: even edge of pair, 1: odd edge
    const int q = lane & 31;         // column quarter: cols 4q..4q+3

    int beg = offsets[node], end = offsets[node + 1];
    float4 acc = make_float4(-3.4e38f, -3.4e38f, -3.4e38f, -3.4e38f);

    for (int e = beg; e < end; e += 8) {
        int i1 = min(e + 1, end - 1);
        int i2 = min(e + 2, end - 1);
        int i3 = min(e + 3, end - 1);
        int i4 = min(e + 4, end - 1);
        int i5 = min(e + 5, end - 1);
        int i6 = min(e + 6, end - 1);
        int i7 = min(e + 7, end - 1);
        uint2 e0 = edges[e],  e1 = edges[i1], e2 = edges[i2], e3 = edges[i3];
        uint2 e4 = edges[i4], e5 = edges[i5], e6 = edges[i6], e7 = edges[i7];
        uint2 mA = half ? e1 : e0;
        uint2 mB = half ? e3 : e2;
        uint2 mC = half ? e5 : e4;
        uint2 mD = half ? e7 : e6;
        float wA = __uint_as_float(mA.y);
        float wB = __uint_as_float(mB.y);
        float wC = __uint_as_float(mC.y);
        float wD = __uint_as_float(mD.y);
        uint2 pA = *(const uint2*)(hb + (size_t)mA.x * DF + q * 4);
        uint2 pB = *(const uint2*)(hb + (size_t)mB.x * DF + q * 4);
        uint2 pC = *(const uint2*)(hb + (size_t)mC.x * DF + q * 4);
        uint2 pD = *(const uint2*)(hb + (size_t)mD.x * DF + q * 4);
        acc.x = fmaxf(acc.x, __uint_as_float(pA.x << 16)          * wA);
        acc.y = fmaxf(acc.y, __uint_as_float(pA.x & 0xffff0000u)  * wA);
        acc.z = fmaxf(acc.z, __uint_as_float(pA.y << 16)          * wA);
        acc.w = fmaxf(acc.w, __uint_as_float(pA.y & 0xffff0000u)  * wA);
        acc.x = fmaxf(acc.x, __uint_as_float(pB.x << 16)          * wB);
        acc.y = fmaxf(acc.y, __uint_as_float(pB.x & 0xffff0000u)  * wB);
        acc.z = fmaxf(acc.z, __uint_as_float(pB.y << 16)          * wB);
        acc.w = fmaxf(acc.w, __uint_as_float(pB.y & 0xffff0000u)  * wB);
        acc.x = fmaxf(acc.x, __uint_as_float(pC.x << 16)          * wC);
        acc.y = fmaxf(acc.y, __uint_as_float(pC.x & 0xffff0000u)  * wC);
        acc.z = fmaxf(acc.z, __uint_as_float(pC.y << 16)          * wC);
        acc.w = fmaxf(acc.w, __uint_as_float(pC.y & 0xffff0000u)  * wC);
        acc.x = fmaxf(acc.x, __uint_as_float(pD.x << 16)          * wD);
        acc.y = fmaxf(acc.y, __uint_as_float(pD.x & 0xffff0000u)  * wD);
        acc.z = fmaxf(acc.z, __uint_as_float(pD.y << 16)          * wD);
        acc.w = fmaxf(acc.w, __uint_as_float(pD.y & 0xffff0000u)  * wD);
    }

    float4 o;
    o.x = fmaxf(acc.x, __shfl_xor(acc.x, 32));
    o.y = fmaxf(acc.y, __shfl_xor(acc.y, 32));
    o.z = fmaxf(acc.z, __shfl_xor(acc.z, 32));
    o.w = fmaxf(acc.w, __shfl_xor(acc.w, 32));
    if (beg == end) o = make_float4(0.f, 0.f, 0.f, 0.f);
    if (half == 0) {
        ushort4 ob;
        ob.x = f2bf(o.x); ob.y = f2bf(o.y); ob.z = f2bf(o.z); ob.w = f2bf(o.w);
        *(ushort4*)(neighb + (size_t)node * DF + q * 4) = ob;
    }
}

// ================= K4: out = featb@Wn1^T + neighb@Wn2^T + b_neigh (fp32) ====
__global__ __launch_bounds__(256) void gemm_out(
    const unsigned short* __restrict__ featb,
    const unsigned short* __restrict__ neighb,
    const unsigned short* __restrict__ Wn1_f,
    const unsigned short* __restrict__ Wn2_f,
    const float* __restrict__ bias,
    float* __restrict__ out)
{
    int wave = (blockIdx.x * 256 + threadIdx.x) >> 6;
    int lane = threadIdx.x & 63;
    int m0 = wave * 16;
    if (m0 >= N_NODES) return;
    const int n = lane & 15, quad = lane >> 4;

    f32x4 acc[8];
    #pragma unroll
    for (int c = 0; c < 8; ++c) {
        float bv = bias[c * 16 + n];
        acc[c] = (f32x4){bv, bv, bv, bv};
    }

    const unsigned short* a0 = featb  + (size_t)(m0 + n) * DF + quad * 8;
    const unsigned short* a1 = neighb + (size_t)(m0 + n) * DF + quad * 8;
    #pragma unroll
    for (int t = 0; t < 4; ++t) {
        bf16x8 af = *(const bf16x8*)(a0 + t * 32);
        #pragma unroll
        for (int c = 0; c < 8; ++c) {
            bf16x8 bf = *(const bf16x8*)(Wn1_f + (size_t)((c * 4 + t) * 64 + lane) * 8);
            acc[c] = __builtin_amdgcn_mfma_f32_16x16x32_bf16(af, bf, acc[c], 0, 0, 0);
        }
    }
    #pragma unroll
    for (int t = 0; t < 4; ++t) {
        bf16x8 af = *(const bf16x8*)(a1 + t * 32);
        #pragma unroll
        for (int c = 0; c < 8; ++c) {
            bf16x8 bf = *(const bf16x8*)(Wn2_f + (size_t)((c * 4 + t) * 64 + lane) * 8);
            acc[c] = __builtin_amdgcn_mfma_f32_16x16x32_bf16(af, bf, acc[c], 0, 0, 0);
        }
    }

    #pragma unroll
    for (int c = 0; c < 8; ++c)
        #pragma unroll
        for (int r = 0; r < 4; ++r)
            out[(size_t)(m0 + quad * 4 + r) * DF + c * 16 + n] = acc[c][r];
}

extern "C" void kernel_launch(void* const* d_in, const int* in_sizes, int n_in,
                              void* d_out, int out_size, void* d_ws, size_t ws_size,
                              hipStream_t stream) {
    const float* feat    = (const float*)d_in[0];
    const float* weight  = (const float*)d_in[1];
    const int*   src     = (const int*)d_in[2];
    const int*   dst     = (const int*)d_in[3];
    const float* W_pool  = (const float*)d_in[4];
    const float* b_pool  = (const float*)d_in[5];
    const float* W_neigh = (const float*)d_in[6];
    const float* b_neigh = (const float*)d_in[7];
    float* out = (float*)d_out;

    char* ws = (char*)d_ws;
    unsigned short* featb  = (unsigned short*)(ws);              // 12,800,000 B
    unsigned short* hb     = (unsigned short*)(ws + 12800000);   // 12,800,000 B
    unsigned short* neighb = (unsigned short*)(ws + 25600000);   // 12,800,000 B
    unsigned short* Wp_f   = (unsigned short*)(ws + 38400000);   // 32,768 B
    unsigned short* Wn1_f  = (unsigned short*)(ws + 38432768);   // 32,768 B
    unsigned short* Wn2_f  = (unsigned short*)(ws + 38465536);   // 32,768 B
    int*   offsets   = (int*)  (ws + 38498304);                  // 200,064 B
    int*   bucketcnt = (int*)  (ws + 38698368);                  // 1,024 B
    uint2* staging   = (uint2*)(ws + 38699392);                  // 9,633,792 B
    uint2* edges     = (uint2*)(ws + 48333184);                  // 5,120,000 B -> ~53.5 MB

    hipMemsetAsync(bucketcnt, 0, 1024, stream);

    // K1: PassA (coarse bucket scatter) || featb conversion || W fragments
    const int K1_BLOCKS = PA_BLOCKS + NF4 / 256 + NWG / 256;   // 250+6250+24
    k1_setup_bucket<<<K1_BLOCKS, 256, 0, stream>>>(
        feat, W_pool, W_neigh, src, dst, weight,
        featb, Wp_f, Wn1_f, Wn2_f, bucketcnt, staging);

    // K2: gemm_pool (hb) || PassB (offsets + final dst-sorted edges)
    k2_gemm_passb<<<GEMMB + NBUCK, 1024, 0, stream>>>(
        featb, Wp_f, b_pool, hb, bucketcnt, staging, offsets, edges);

    // K3: neighb = bf16(segment_max(hb[src]*w, dst)), 0 for empty
    neigh_max_kernel<<<(N_NODES + 3) / 4, 256, 0, stream>>>(hb, offsets, edges, neighb);

    // K4: out = featb @ Wn1^T + neighb @ Wn2^T + b_neigh
    gemm_out<<<782, 256, 0, stream>>>(
        featb, neighb, Wn1_f, Wn2_f, b_neigh, out);
}